// Round 7
// baseline (152.516 us; speedup 1.0000x reference)
//
#include <hip/hip_runtime.h>
#include <hip/hip_bf16.h>

// B=2000 graphs, LGPG=100 line-graph nodes/graph, NPG=20, ELPG=10, D=300.
#define D_      300
#define H2_     200       // cols [0,200) <- incoming (idx[:,1]), [200,300) <- outgoing (idx[:,0])
#define NPGMAX  20
#define ROWMAX  128
#define BN_     2000
#define NNODES_ 40000
#define ELAB_   20000
#define TPB_    320       // 5 waves; threads 0..299 own one column each
#define BATCH_  8

__global__ __launch_bounds__(TPB_) void main_kernel(
    const float* __restrict__ x, const int* __restrict__ lgidx,
    const int* __restrict__ ptr, const int* __restrict__ ogs,
    const int* __restrict__ els, const int* __restrict__ edge_in,
    float* __restrict__ out)
{
    // Output layout (f32 element offsets): x_new@0 [40000,300], edge@12,000,000 [2,20000],
    // ptr_new@12,040,000 [2001], batch@12,042,001 [40000].
    float* __restrict__ out_x     = out;
    float* __restrict__ out_edge  = out + (size_t)NNODES_ * D_;
    float* __restrict__ out_ptr   = out + (size_t)NNODES_ * D_ + 2 * ELAB_;
    float* __restrict__ out_batch = out + (size_t)NNODES_ * D_ + 2 * ELAB_ + (BN_ + 1);

    __shared__ int sidx[ROWMAX * 2];
    __shared__ int pool_in[ROWMAX], pool_out[ROWMAX];
    __shared__ int cnt_in[NPGMAX], cnt_out[NPGMAX];
    __shared__ int off_in[NPGMAX + 1], off_out[NPGMAX + 1];
    __shared__ int s_r1[256], s_r2[256];

    const int g = blockIdx.x;
    const int t = threadIdx.x;

    // ---- Exclusive prefix of ogs/els over graphs [0,g) (256 participants). ----
    if (t < 256) {
        int p1 = 0, p2 = 0;
        for (int k = t; k < g; k += 256) { p1 += ogs[k]; p2 += els[k]; }
        s_r1[t] = p1; s_r2[t] = p2;
    }
    __syncthreads();
    for (int s = 128; s > 0; s >>= 1) {
        if (t < s) { s_r1[t] += s_r1[t + s]; s_r2[t] += s_r2[t + s]; }
        __syncthreads();
    }
    const int nbase = s_r1[0];
    const int eb    = s_r2[0];

    const int lg0 = ptr[g], lg1 = ptr[g + 1];
    int nrow = lg1 - lg0; if (nrow > ROWMAX) nrow = ROWMAX; if (nrow < 0) nrow = 0;
    const int npg_true = ogs[g];
    int npg = npg_true; if (npg > NPGMAX) npg = NPGMAX;
    __syncthreads();

    if (t < NPGMAX) { cnt_in[t] = 0; cnt_out[t] = 0; }
    for (int i = t; i < nrow * 2; i += TPB_) sidx[i] = lgidx[(size_t)lg0 * 2 + i];
    __syncthreads();

    if (t < nrow) {
        atomicAdd(&cnt_out[sidx[2 * t]], 1);      // native ds_add_u32
        atomicAdd(&cnt_in[sidx[2 * t + 1]], 1);
    }
    __syncthreads();

    if (t == 0) {
        int a = 0, b = 0;
        for (int n = 0; n < NPGMAX; ++n) {
            off_in[n] = a;  a += cnt_in[n];
            off_out[n] = b; b += cnt_out[n];
        }
        off_in[NPGMAX] = a; off_out[NPGMAX] = b;
    }
    __syncthreads();

    // Deterministic CSR fill: slot = off[n] + #{r' < r : seg(r')==n}.
    if (t < nrow) {
        const int nin = sidx[2 * t + 1], nou = sidx[2 * t];
        int pin = 0, pou = 0;
        for (int r = 0; r < t; ++r) {
            pin += (sidx[2 * r + 1] == nin);
            pou += (sidx[2 * r]     == nou);
        }
        pool_in[off_in[nin] + pin]   = t;
        pool_out[off_out[nou] + pou] = t;
    }
    __syncthreads();

    // ---- Main gather: thread t owns column c=t. Linear sweep over the
    // segment-sorted pool with 8-deep load batches (8 global loads in flight
    // per wave), emitting per-segment means at uniform-per-lane boundaries. ----
    if (t < D_) {
        const int c = t;
        const bool inc = (c < H2_);
        const int* __restrict__ pool = inc ? pool_in : pool_out;
        const int* __restrict__ off  = inc ? off_in  : off_out;
        const float* __restrict__ xg = x + (size_t)lg0 * D_ + c;
        float* __restrict__ outp = out_x + (size_t)nbase * D_ + c;

        const int total = off[npg];   // == nrow
        float s = 0.0f;
        int n = 0;
        // leading empty segments
        while (n < npg && off[n + 1] == 0) { outp[(size_t)n * D_] = 0.0f; ++n; }

        int k = 0;
        while (k < total) {
            float v[BATCH_];
            const int m = (total - k < BATCH_) ? (total - k) : BATCH_;
            #pragma unroll
            for (int j = 0; j < BATCH_; ++j)
                if (j < m) v[j] = xg[(size_t)pool[k + j] * D_];
            #pragma unroll
            for (int j = 0; j < BATCH_; ++j) {
                if (j < m) {
                    s += v[j];
                    const int kk = k + j + 1;
                    while (n < npg && kk == off[n + 1]) {
                        const int cnt = off[n + 1] - off[n];
                        outp[(size_t)n * D_] = (cnt > 0) ? s / (float)cnt : 0.0f;
                        s = 0.0f;
                        ++n;
                    }
                }
            }
            k += m;
        }
        // trailing empty segments (defensive; normally popped above)
        while (n < npg) {
            outp[(size_t)n * D_] = 0.0f;
            ++n;
        }
    }

    // ---- Small outputs. ----
    if (t == 0) {
        out_ptr[g + 1] = (float)(nbase + npg_true);
        if (g == 0) out_ptr[0] = 0.0f;
    }
    for (int i = t; i < npg_true; i += TPB_)
        out_batch[nbase + i] = (float)g;

    const int nel = els[g];
    const int lgoff = lg0 - ptr[0];
    for (int j = t; j < nel; j += TPB_) {
        out_edge[eb + j]                 = (float)(edge_in[eb + j] - lgoff);
        out_edge[(size_t)ELAB_ + eb + j] = (float)(edge_in[(size_t)ELAB_ + eb + j] - lgoff);
    }
}

extern "C" void kernel_launch(void* const* d_in, const int* in_sizes, int n_in,
                              void* d_out, int out_size, void* d_ws, size_t ws_size,
                              hipStream_t stream)
{
    const float* x        = (const float*)d_in[0];
    const int*   lgidx    = (const int*)d_in[1];
    const int*   ptr      = (const int*)d_in[2];
    const int*   ogs      = (const int*)d_in[3];
    const int*   els      = (const int*)d_in[4];
    const int*   edge_in  = (const int*)d_in[5];

    main_kernel<<<BN_, TPB_, 0, stream>>>(x, lgidx, ptr, ogs, els, edge_in,
                                          (float*)d_out);
}

// Round 8
// 73.479 us; speedup vs baseline: 2.0756x; 2.0756x over previous
//
#include <hip/hip_runtime.h>
#include <hip/hip_bf16.h>

// B=2000 graphs, LGPG=100 line-graph nodes/graph, NPG=20, ELPG=10, D=300.
#define D_      300
#define H2_     200       // cols [0,200) <- incoming (idx[:,1]), [200,300) <- outgoing (idx[:,0])
#define NPGMAX  20
#define ROWMAX  128
#define BN_     2000
#define NNODES_ 40000
#define ELAB_   20000
#define TPB_    320       // 5 waves; threads 0..299 own one column each
#define BATCH_  8

__global__ __launch_bounds__(TPB_) void main_kernel(
    const float* __restrict__ x, const int* __restrict__ lgidx,
    const int* __restrict__ ptr, const int* __restrict__ ogs,
    const int* __restrict__ els, const int* __restrict__ edge_in,
    float* __restrict__ out)
{
    // Output layout (f32 element offsets): x_new@0 [40000,300], edge@12,000,000 [2,20000],
    // ptr_new@12,040,000 [2001], batch@12,042,001 [40000].
    float* __restrict__ out_x     = out;
    float* __restrict__ out_edge  = out + (size_t)NNODES_ * D_;
    float* __restrict__ out_ptr   = out + (size_t)NNODES_ * D_ + 2 * ELAB_;
    float* __restrict__ out_batch = out + (size_t)NNODES_ * D_ + 2 * ELAB_ + (BN_ + 1);

    __shared__ int   sidx[ROWMAX * 2];
    __shared__ int   pool_in[ROWMAX + BATCH_], pool_out[ROWMAX + BATCH_];
    __shared__ int   endseg_in[ROWMAX + BATCH_], endseg_out[ROWMAX + BATCH_];
    __shared__ float inv_in[NPGMAX], inv_out[NPGMAX];
    __shared__ int   cnt_in[NPGMAX], cnt_out[NPGMAX];
    __shared__ int   off_in[NPGMAX + 1], off_out[NPGMAX + 1];
    __shared__ int   s_r1[256], s_r2[256];

    const int g = blockIdx.x;
    const int t = threadIdx.x;

    // ---- Exclusive prefix of ogs/els over graphs [0,g) (256 participants). ----
    if (t < 256) {
        int p1 = 0, p2 = 0;
        for (int k = t; k < g; k += 256) { p1 += ogs[k]; p2 += els[k]; }
        s_r1[t] = p1; s_r2[t] = p2;
    }
    __syncthreads();
    for (int s = 128; s > 0; s >>= 1) {
        if (t < s) { s_r1[t] += s_r1[t + s]; s_r2[t] += s_r2[t + s]; }
        __syncthreads();
    }
    const int nbase = s_r1[0];
    const int eb    = s_r2[0];

    const int lg0 = ptr[g], lg1 = ptr[g + 1];
    int nrow = lg1 - lg0; if (nrow > ROWMAX) nrow = ROWMAX; if (nrow < 0) nrow = 0;
    const int npg_true = ogs[g];
    int npg = npg_true; if (npg > NPGMAX) npg = NPGMAX;
    __syncthreads();

    if (t < NPGMAX) { cnt_in[t] = 0; cnt_out[t] = 0; }
    for (int i = t; i < ROWMAX + BATCH_; i += TPB_) {
        pool_in[i] = 0; pool_out[i] = 0;
        endseg_in[i] = -1; endseg_out[i] = -1;
    }
    for (int i = t; i < nrow * 2; i += TPB_) sidx[i] = lgidx[(size_t)lg0 * 2 + i];
    __syncthreads();

    if (t < nrow) {
        atomicAdd(&cnt_out[sidx[2 * t]], 1);      // native ds_add_u32
        atomicAdd(&cnt_in[sidx[2 * t + 1]], 1);
    }
    __syncthreads();

    if (t == 0) {
        int a = 0, b = 0;
        for (int n = 0; n < NPGMAX; ++n) {
            off_in[n] = a;  a += cnt_in[n];
            off_out[n] = b; b += cnt_out[n];
        }
        off_in[NPGMAX] = a; off_out[NPGMAX] = b;
    }
    __syncthreads();

    // Per-segment helpers: last-row marker + inverse count.
    if (t < NPGMAX) {
        const int ci = cnt_in[t], co = cnt_out[t];
        inv_in[t]  = (ci > 0) ? 1.0f / (float)ci : 0.0f;
        inv_out[t] = (co > 0) ? 1.0f / (float)co : 0.0f;
        if (ci > 0) endseg_in[off_in[t + 1] - 1] = t;
        if (co > 0) endseg_out[off_out[t + 1] - 1] = t;
    }

    // Deterministic CSR fill: slot = off[n] + #{r' < r : seg(r')==n}.
    if (t < nrow) {
        const int nin = sidx[2 * t + 1], nou = sidx[2 * t];
        int pin = 0, pou = 0;
        for (int r = 0; r < t; ++r) {
            pin += (sidx[2 * r + 1] == nin);
            pou += (sidx[2 * r]     == nou);
        }
        pool_in[off_in[nin] + pin]   = t;
        pool_out[off_out[nou] + pou] = t;
    }
    __syncthreads();

    // ---- Main gather: thread t owns column c=t. Linear sweep over the
    // segment-sorted padded pool; 8 UNCONDITIONAL coalesced loads per batch
    // (true 8-deep pipe), boundaries via endseg[] predication. ----
    if (t < D_) {
        const int c = t;
        const bool inc = (c < H2_);
        const int*   __restrict__ pool   = inc ? pool_in   : pool_out;
        const int*   __restrict__ off    = inc ? off_in    : off_out;
        const int*   __restrict__ endseg = inc ? endseg_in : endseg_out;
        const float* __restrict__ invc   = inc ? inv_in    : inv_out;
        const float* __restrict__ xg = x + (size_t)lg0 * D_ + c;
        float* __restrict__ outp = out_x + (size_t)nbase * D_ + c;

        // Empty segments -> 0 (rare; cheap scan).
        for (int n = 0; n < npg; ++n)
            if (off[n + 1] == off[n]) outp[(size_t)n * D_] = 0.0f;

        const int total  = off[npg];              // == nrow
        const int totalp = (total + BATCH_ - 1) & ~(BATCH_ - 1);
        float s = 0.0f;
        for (int k = 0; k < totalp; k += BATCH_) {
            float v[BATCH_];
            #pragma unroll
            for (int j = 0; j < BATCH_; ++j)      // unconditional: pool is padded
                v[j] = xg[(size_t)pool[k + j] * D_];
            #pragma unroll
            for (int j = 0; j < BATCH_; ++j) {
                const int kk = k + j;
                if (kk < total) {
                    s += v[j];
                    const int e = endseg[kk];
                    if (e >= 0) { outp[(size_t)e * D_] = s * invc[e]; s = 0.0f; }
                }
            }
        }
    }

    // ---- Small outputs. ----
    if (t == 0) {
        out_ptr[g + 1] = (float)(nbase + npg_true);
        if (g == 0) out_ptr[0] = 0.0f;
    }
    for (int i = t; i < npg_true; i += TPB_)
        out_batch[nbase + i] = (float)g;

    const int nel = els[g];
    const int lgoff = lg0 - ptr[0];
    for (int j = t; j < nel; j += TPB_) {
        out_edge[eb + j]                 = (float)(edge_in[eb + j] - lgoff);
        out_edge[(size_t)ELAB_ + eb + j] = (float)(edge_in[(size_t)ELAB_ + eb + j] - lgoff);
    }
}

extern "C" void kernel_launch(void* const* d_in, const int* in_sizes, int n_in,
                              void* d_out, int out_size, void* d_ws, size_t ws_size,
                              hipStream_t stream)
{
    const float* x        = (const float*)d_in[0];
    const int*   lgidx    = (const int*)d_in[1];
    const int*   ptr      = (const int*)d_in[2];
    const int*   ogs      = (const int*)d_in[3];
    const int*   els      = (const int*)d_in[4];
    const int*   edge_in  = (const int*)d_in[5];

    main_kernel<<<BN_, TPB_, 0, stream>>>(x, lgidx, ptr, ogs, els, edge_in,
                                          (float*)d_out);
}